// Round 1
// baseline (101.477 us; speedup 1.0000x reference)
//
#include <hip/hip_runtime.h>

#define HH 128
#define WW 128
#define KK 8
#define TILE 16
#define TX (WW / TILE)        // 8
#define TY (HH / TILE)        // 8
#define NTILES (TX * TY)      // 64
#define CHUNK 256
#define CAP_MAX 2048

// ws layout: counts[NTILES] (int) | lists[NTILES * cap] (int)

__global__ void bin_points_kernel(const float* __restrict__ pts,
                                  const float* __restrict__ rad,
                                  int P, int cap,
                                  int* __restrict__ counts,
                                  int* __restrict__ lists) {
    __shared__ int scount[NTILES];
    int tid = threadIdx.x;
    if (tid < NTILES) scount[tid] = 0;
    __syncthreads();

    for (int p = tid; p < P; p += blockDim.x) {
        float x = pts[3 * p + 0];
        float y = pts[3 * p + 1];
        float z = pts[3 * p + 2];
        float r = rad[p];
        if (!(z >= 0.0f) || !(r > 0.0f)) continue;

        // pixel centers: xf(w) = 1 - (2w+1)/W (decreasing in w)
        // point touches pixel w only if |xf(w) - x| < r  ->  w in open interval
        float wlo = (WW * (1.0f - x - r) - 1.0f) * 0.5f;
        float whi = (WW * (1.0f - x + r) - 1.0f) * 0.5f;
        int wmin = max(0, (int)ceilf(wlo - 1.0f));       // widened 1px for fp slop
        int wmax = min(WW - 1, (int)floorf(whi + 1.0f));
        float hlo = (HH * (1.0f - y - r) - 1.0f) * 0.5f;
        float hhi = (HH * (1.0f - y + r) - 1.0f) * 0.5f;
        int hmin = max(0, (int)ceilf(hlo - 1.0f));
        int hmax = min(HH - 1, (int)floorf(hhi + 1.0f));
        if (wmin > wmax || hmin > hmax) continue;

        int twmin = wmin / TILE, twmax = wmax / TILE;
        int thmin = hmin / TILE, thmax = hmax / TILE;
        for (int th = thmin; th <= thmax; ++th) {
            for (int tw = twmin; tw <= twmax; ++tw) {
                int t = th * TX + tw;
                int slot = atomicAdd(&scount[t], 1);
                if (slot < cap) lists[t * cap + slot] = p;
            }
        }
    }
    __syncthreads();
    if (tid < NTILES) counts[tid] = min(scount[tid], cap);
}

__global__ void raster_kernel(const float* __restrict__ pts,
                              const float* __restrict__ rad,
                              const int* __restrict__ counts,
                              const int* __restrict__ lists,
                              int cap,
                              float* __restrict__ out) {
    int t = blockIdx.x;
    int th = t / TX, tw = t % TX;
    int tid = threadIdx.x;
    int pw = tid % TILE, ph = tid / TILE;
    int w = tw * TILE + pw;
    int h = th * TILE + ph;

    float xf = 1.0f - (2.0f * (float)w + 1.0f) * (1.0f / (float)WW);
    float yf = 1.0f - (2.0f * (float)h + 1.0f) * (1.0f / (float)HH);

    __shared__ float sx[CHUNK], sy[CHUNK], szv[CHUNK], sr2[CHUNK];
    __shared__ int spi[CHUNK];

    // top-K sorted ascending by (z, idx); empty = (+inf, INT_MAX)
    float bz[KK]; int bi[KK]; float bd[KK];
#pragma unroll
    for (int k = 0; k < KK; ++k) { bz[k] = INFINITY; bi[k] = 0x7fffffff; bd[k] = -1.0f; }

    int cnt = counts[t];
    for (int base = 0; base < cnt; base += CHUNK) {
        int n = min(CHUNK, cnt - base);
        __syncthreads();
        if (tid < n) {
            int p = lists[t * cap + base + tid];
            spi[tid] = p;
            sx[tid] = pts[3 * p + 0];
            sy[tid] = pts[3 * p + 1];
            szv[tid] = pts[3 * p + 2];
            float r = rad[p];
            sr2[tid] = __fmul_rn(r, r);
        }
        __syncthreads();

        for (int j = 0; j < n; ++j) {
            float x = sx[j], y = sy[j], z = szv[j], r2 = sr2[j];
            int p = spi[j];
            float dx = xf - x;
            float dy = yf - y;
            // match numpy rounding exactly: mul, mul, add (no fma contraction)
            float d2 = __fadd_rn(__fmul_rn(dx, dx), __fmul_rn(dy, dy));
            if (d2 < r2) {
                // lexicographic (z, idx) beats current worst?
                bool better = (z < bz[KK - 1]) || (z == bz[KK - 1] && p < bi[KK - 1]);
                if (better) {
                    bz[KK - 1] = z; bi[KK - 1] = p; bd[KK - 1] = d2;
#pragma unroll
                    for (int k = KK - 1; k > 0; --k) {
                        bool sw = (bz[k] < bz[k - 1]) ||
                                  (bz[k] == bz[k - 1] && bi[k] < bi[k - 1]);
                        if (sw) {
                            float tz = bz[k]; bz[k] = bz[k - 1]; bz[k - 1] = tz;
                            int   ti = bi[k]; bi[k] = bi[k - 1]; bi[k - 1] = ti;
                            float td = bd[k]; bd[k] = bd[k - 1]; bd[k - 1] = td;
                        }
                    }
                }
            }
        }
    }

    int pix = h * WW + w;
    float* o_idx = out;
    float* o_z   = out + HH * WW * KK;
    float* o_d   = out + 2 * HH * WW * KK;
#pragma unroll
    for (int k = 0; k < KK; ++k) {
        bool v = (bi[k] != 0x7fffffff);
        o_idx[pix * KK + k] = v ? (float)bi[k] : -1.0f;
        o_z[pix * KK + k]   = v ? bz[k]        : -1.0f;
        o_d[pix * KK + k]   = v ? bd[k]        : -1.0f;
    }
}

extern "C" void kernel_launch(void* const* d_in, const int* in_sizes, int n_in,
                              void* d_out, int out_size, void* d_ws, size_t ws_size,
                              hipStream_t stream) {
    const float* pts = (const float*)d_in[0];   // (P,3) f32
    const float* rad = (const float*)d_in[1];   // (P,)  f32
    int P = in_sizes[0] / 3;

    int* counts = (int*)d_ws;
    int* lists  = counts + NTILES;

    // capacity per tile list, bounded by workspace
    long avail = (long)(ws_size / sizeof(int)) - NTILES;
    int cap = (int)(avail / NTILES);
    if (cap > CAP_MAX) cap = CAP_MAX;
    if (cap < 1) cap = 1;

    bin_points_kernel<<<1, 256, 0, stream>>>(pts, rad, P, cap, counts, lists);
    raster_kernel<<<NTILES, 256, 0, stream>>>(pts, rad, counts, lists, cap, (float*)d_out);
}

// Round 2
// 75.203 us; speedup vs baseline: 1.3494x; 1.3494x over previous
//
#include <hip/hip_runtime.h>

#define HH 128
#define WW 128
#define KK 8
#define TILE 8
#define TX (WW / TILE)        // 16
#define TY (HH / TILE)        // 16
#define NTILES (TX * TY)      // 256
#define CHUNK 64
#define CAP_MAX 1024

// ws layout: counts[NTILES] (int) | lists[NTILES * cap] (int)

__global__ void bin_points_kernel(const float* __restrict__ pts,
                                  const float* __restrict__ rad,
                                  int P, int cap,
                                  int* __restrict__ counts,
                                  int* __restrict__ lists) {
    int p = blockIdx.x * blockDim.x + threadIdx.x;
    if (p >= P) return;

    float x = pts[3 * p + 0];
    float y = pts[3 * p + 1];
    float z = pts[3 * p + 2];
    float r = rad[p];
    if (!(z >= 0.0f) || !(r > 0.0f)) return;

    // pixel centers: xf(w) = 1 - (2w+1)/W (decreasing in w)
    // point touches pixel w only if |xf(w) - x| < r  ->  w in open interval
    float wlo = (WW * (1.0f - x - r) - 1.0f) * 0.5f;
    float whi = (WW * (1.0f - x + r) - 1.0f) * 0.5f;
    int wmin = max(0, (int)ceilf(wlo - 1.0f));       // widened 1px for fp slop
    int wmax = min(WW - 1, (int)floorf(whi + 1.0f));
    float hlo = (HH * (1.0f - y - r) - 1.0f) * 0.5f;
    float hhi = (HH * (1.0f - y + r) - 1.0f) * 0.5f;
    int hmin = max(0, (int)ceilf(hlo - 1.0f));
    int hmax = min(HH - 1, (int)floorf(hhi + 1.0f));
    if (wmin > wmax || hmin > hmax) return;

    int twmin = wmin / TILE, twmax = wmax / TILE;
    int thmin = hmin / TILE, thmax = hmax / TILE;
    for (int th = thmin; th <= thmax; ++th) {
        for (int tw = twmin; tw <= twmax; ++tw) {
            int t = th * TX + tw;
            int slot = atomicAdd(&counts[t], 1);
            if (slot < cap) lists[t * cap + slot] = p;
        }
    }
}

__global__ void raster_kernel(const float* __restrict__ pts,
                              const float* __restrict__ rad,
                              const int* __restrict__ counts,
                              const int* __restrict__ lists,
                              int cap,
                              float* __restrict__ out) {
    int t = blockIdx.x;
    int th = t / TX, tw = t % TX;
    int tid = threadIdx.x;
    int pw = tid % TILE, ph = tid / TILE;
    int w = tw * TILE + pw;
    int h = th * TILE + ph;

    float xf = 1.0f - (2.0f * (float)w + 1.0f) * (1.0f / (float)WW);
    float yf = 1.0f - (2.0f * (float)h + 1.0f) * (1.0f / (float)HH);

    __shared__ float sx[CHUNK], sy[CHUNK], szv[CHUNK], sr2[CHUNK];
    __shared__ int spi[CHUNK];

    // top-K sorted ascending by (z, idx); empty = (+inf, INT_MAX)
    float bz[KK]; int bi[KK]; float bd[KK];
#pragma unroll
    for (int k = 0; k < KK; ++k) { bz[k] = INFINITY; bi[k] = 0x7fffffff; bd[k] = -1.0f; }

    int cnt = min(counts[t], cap);
    for (int base = 0; base < cnt; base += CHUNK) {
        int n = min(CHUNK, cnt - base);
        __syncthreads();
        if (tid < n) {
            int p = lists[t * cap + base + tid];
            spi[tid] = p;
            sx[tid] = pts[3 * p + 0];
            sy[tid] = pts[3 * p + 1];
            szv[tid] = pts[3 * p + 2];
            float r = rad[p];
            sr2[tid] = __fmul_rn(r, r);
        }
        __syncthreads();

        for (int j = 0; j < n; ++j) {
            float x = sx[j], y = sy[j], z = szv[j], r2 = sr2[j];
            int p = spi[j];
            float dx = xf - x;
            float dy = yf - y;
            // match numpy rounding exactly: mul, mul, add (no fma contraction)
            float d2 = __fadd_rn(__fmul_rn(dx, dx), __fmul_rn(dy, dy));
            if (d2 < r2) {
                // lexicographic (z, idx) beats current worst?
                bool better = (z < bz[KK - 1]) || (z == bz[KK - 1] && p < bi[KK - 1]);
                if (better) {
                    bz[KK - 1] = z; bi[KK - 1] = p; bd[KK - 1] = d2;
#pragma unroll
                    for (int k = KK - 1; k > 0; --k) {
                        bool sw = (bz[k] < bz[k - 1]) ||
                                  (bz[k] == bz[k - 1] && bi[k] < bi[k - 1]);
                        if (sw) {
                            float tz = bz[k]; bz[k] = bz[k - 1]; bz[k - 1] = tz;
                            int   ti = bi[k]; bi[k] = bi[k - 1]; bi[k - 1] = ti;
                            float td = bd[k]; bd[k] = bd[k - 1]; bd[k - 1] = td;
                        }
                    }
                }
            }
        }
    }

    int pix = h * WW + w;
    float* o_idx = out;
    float* o_z   = out + HH * WW * KK;
    float* o_d   = out + 2 * HH * WW * KK;
#pragma unroll
    for (int k = 0; k < KK; ++k) {
        bool v = (bi[k] != 0x7fffffff);
        o_idx[pix * KK + k] = v ? (float)bi[k] : -1.0f;
        o_z[pix * KK + k]   = v ? bz[k]        : -1.0f;
        o_d[pix * KK + k]   = v ? bd[k]        : -1.0f;
    }
}

extern "C" void kernel_launch(void* const* d_in, const int* in_sizes, int n_in,
                              void* d_out, int out_size, void* d_ws, size_t ws_size,
                              hipStream_t stream) {
    const float* pts = (const float*)d_in[0];   // (P,3) f32
    const float* rad = (const float*)d_in[1];   // (P,)  f32
    int P = in_sizes[0] / 3;

    int* counts = (int*)d_ws;
    int* lists  = counts + NTILES;

    // capacity per tile list, bounded by workspace
    long avail = (long)(ws_size / sizeof(int)) - NTILES;
    int cap = (int)(avail / NTILES);
    if (cap > CAP_MAX) cap = CAP_MAX;
    if (cap < 1) cap = 1;

    hipMemsetAsync(counts, 0, NTILES * sizeof(int), stream);
    bin_points_kernel<<<(P + 255) / 256, 256, 0, stream>>>(pts, rad, P, cap, counts, lists);
    raster_kernel<<<NTILES, TILE * TILE, 0, stream>>>(pts, rad, counts, lists, cap, (float*)d_out);
}

// Round 3
// 72.066 us; speedup vs baseline: 1.4081x; 1.0435x over previous
//
#include <hip/hip_runtime.h>

#define HH 128
#define WW 128
#define KK 8
#define TILE 8
#define TX (WW / TILE)        // 16
#define TY (HH / TILE)        // 16
#define NTILES (TX * TY)      // 256
#define CAP_MAX 1024

// ws layout: counts[NTILES] int (1 KB) | xyzr[NTILES*cap] float4 | pidx[NTILES*cap] int
// per-slot cost: 20 bytes per tile entry

__device__ __forceinline__ float bcastf(float v, int lane) {
    return __int_as_float(__builtin_amdgcn_readlane(__float_as_int(v), lane));
}
__device__ __forceinline__ int bcasti(int v, int lane) {
    return __builtin_amdgcn_readlane(v, lane);
}

__global__ void bin_points_kernel(const float* __restrict__ pts,
                                  const float* __restrict__ rad,
                                  int P, int cap,
                                  int* __restrict__ counts,
                                  float4* __restrict__ xyzr,
                                  int* __restrict__ pidx) {
    int p = blockIdx.x * blockDim.x + threadIdx.x;
    if (p >= P) return;

    float x = pts[3 * p + 0];
    float y = pts[3 * p + 1];
    float z = pts[3 * p + 2];
    float r = rad[p];
    if (!(z >= 0.0f) || !(r > 0.0f)) return;

    // pixel centers: xf(w) = 1 - (2w+1)/W (decreasing in w)
    // point touches pixel w only if |xf(w) - x| < r; widened 1px for fp slop
    float wlo = (WW * (1.0f - x - r) - 1.0f) * 0.5f;
    float whi = (WW * (1.0f - x + r) - 1.0f) * 0.5f;
    int wmin = max(0, (int)ceilf(wlo - 1.0f));
    int wmax = min(WW - 1, (int)floorf(whi + 1.0f));
    float hlo = (HH * (1.0f - y - r) - 1.0f) * 0.5f;
    float hhi = (HH * (1.0f - y + r) - 1.0f) * 0.5f;
    int hmin = max(0, (int)ceilf(hlo - 1.0f));
    int hmax = min(HH - 1, (int)floorf(hhi + 1.0f));
    if (wmin > wmax || hmin > hmax) return;

    float4 rec = make_float4(x, y, z, __fmul_rn(r, r));

    int twmin = wmin / TILE, twmax = wmax / TILE;
    int thmin = hmin / TILE, thmax = hmax / TILE;
    for (int th = thmin; th <= thmax; ++th) {
        for (int tw = twmin; tw <= twmax; ++tw) {
            int t = th * TX + tw;
            int slot = atomicAdd(&counts[t], 1);
            if (slot < cap) {
                xyzr[t * cap + slot] = rec;
                pidx[t * cap + slot] = p;
            }
        }
    }
}

// one block = one 64-lane wave = one 8x8 pixel tile; no LDS, no syncthreads
__global__ void __launch_bounds__(64) raster_kernel(
                              const int* __restrict__ counts,
                              const float4* __restrict__ xyzr,
                              const int* __restrict__ pidx,
                              int cap,
                              float* __restrict__ out) {
    int t = blockIdx.x;
    int th = t / TX, tw = t % TX;
    int lane = threadIdx.x;
    int pw = lane % TILE, ph = lane / TILE;
    int w = tw * TILE + pw;
    int h = th * TILE + ph;

    float xf = 1.0f - (2.0f * (float)w + 1.0f) * (1.0f / (float)WW);
    float yf = 1.0f - (2.0f * (float)h + 1.0f) * (1.0f / (float)HH);

    // top-K sorted ascending by (z, idx); empty = (+inf, INT_MAX)
    float bz[KK]; int bi[KK]; float bd[KK];
#pragma unroll
    for (int k = 0; k < KK; ++k) { bz[k] = INFINITY; bi[k] = 0x7fffffff; bd[k] = -1.0f; }

    int cnt = min(counts[t], cap);
    const float4* tl = xyzr + (long)t * cap;
    const int*    ti = pidx + (long)t * cap;

    // register double-buffer: lane holds candidate (base + lane)
    float4 cur = make_float4(0.f, 0.f, 0.f, 0.f);
    int cpi = 0;
    if (lane < cnt) { cur = tl[lane]; cpi = ti[lane]; }

    for (int base = 0; base < cnt; base += 64) {
        int n = min(64, cnt - base);
        // prefetch next chunk while we chew on this one
        float4 nxt = make_float4(0.f, 0.f, 0.f, 0.f);
        int npi = 0;
        int nb = base + 64;
        if (nb + lane < cnt) { nxt = tl[nb + lane]; npi = ti[nb + lane]; }

        for (int j = 0; j < n; ++j) {
            float x  = bcastf(cur.x, j);
            float y  = bcastf(cur.y, j);
            float z  = bcastf(cur.z, j);
            float r2 = bcastf(cur.w, j);
            int   p  = bcasti(cpi, j);
            float dx = xf - x;
            float dy = yf - y;
            // match numpy rounding exactly: mul, mul, add (no fma contraction)
            float d2 = __fadd_rn(__fmul_rn(dx, dx), __fmul_rn(dy, dy));
            if (d2 < r2) {
                bool better = (z < bz[KK - 1]) || (z == bz[KK - 1] && p < bi[KK - 1]);
                if (better) {
                    bz[KK - 1] = z; bi[KK - 1] = p; bd[KK - 1] = d2;
#pragma unroll
                    for (int k = KK - 1; k > 0; --k) {
                        bool sw = (bz[k] < bz[k - 1]) ||
                                  (bz[k] == bz[k - 1] && bi[k] < bi[k - 1]);
                        if (sw) {
                            float tz = bz[k]; bz[k] = bz[k - 1]; bz[k - 1] = tz;
                            int   ii = bi[k]; bi[k] = bi[k - 1]; bi[k - 1] = ii;
                            float td = bd[k]; bd[k] = bd[k - 1]; bd[k - 1] = td;
                        }
                    }
                }
            }
        }
        cur = nxt; cpi = npi;
    }

    int pix = h * WW + w;
    float* o_idx = out;
    float* o_z   = out + HH * WW * KK;
    float* o_d   = out + 2 * HH * WW * KK;
#pragma unroll
    for (int k = 0; k < KK; ++k) {
        bool v = (bi[k] != 0x7fffffff);
        o_idx[pix * KK + k] = v ? (float)bi[k] : -1.0f;
        o_z[pix * KK + k]   = v ? bz[k]        : -1.0f;
        o_d[pix * KK + k]   = v ? bd[k]        : -1.0f;
    }
}

extern "C" void kernel_launch(void* const* d_in, const int* in_sizes, int n_in,
                              void* d_out, int out_size, void* d_ws, size_t ws_size,
                              hipStream_t stream) {
    const float* pts = (const float*)d_in[0];   // (P,3) f32
    const float* rad = (const float*)d_in[1];   // (P,)  f32
    int P = in_sizes[0] / 3;

    int* counts = (int*)d_ws;
    // slot cost = 16B (float4) + 4B (idx) per tile entry
    long avail = (long)ws_size - 1024;
    int cap = (int)(avail / (NTILES * 20));
    if (cap > CAP_MAX) cap = CAP_MAX;
    if (cap < 1) cap = 1;
    float4* xyzr = (float4*)((char*)d_ws + 1024);
    int* pidx = (int*)(xyzr + (long)NTILES * cap);

    hipMemsetAsync(counts, 0, NTILES * sizeof(int), stream);
    bin_points_kernel<<<(P + 255) / 256, 256, 0, stream>>>(pts, rad, P, cap, counts, xyzr, pidx);
    raster_kernel<<<NTILES, 64, 0, stream>>>(counts, xyzr, pidx, cap, (float*)d_out);
}

// Round 4
// 58.215 us; speedup vs baseline: 1.7431x; 1.2379x over previous
//
#include <hip/hip_runtime.h>

#define HH 128
#define WW 128
#define KK 8
#define TILE 8
#define TX (WW / TILE)        // 16
#define TY (HH / TILE)        // 16
#define NTILES (TX * TY)      // 256
#define CAP_MAX 1024
#define IMAX 0x7fffffff

// ws layout: counts[NTILES] int (1 KB) | xyzr[NTILES*cap] float4 | pidx[NTILES*cap] int

__device__ __forceinline__ float bcastf(float v, int lane) {
    return __int_as_float(__builtin_amdgcn_readlane(__float_as_int(v), lane));
}
__device__ __forceinline__ int bcasti(int v, int lane) {
    return __builtin_amdgcn_readlane(v, lane);
}

__global__ void bin_points_kernel(const float* __restrict__ pts,
                                  const float* __restrict__ rad,
                                  int P, int cap,
                                  int* __restrict__ counts,
                                  float4* __restrict__ xyzr,
                                  int* __restrict__ pidx) {
    int p = blockIdx.x * blockDim.x + threadIdx.x;
    if (p >= P) return;

    float x = pts[3 * p + 0];
    float y = pts[3 * p + 1];
    float z = pts[3 * p + 2];
    float r = rad[p];
    if (!(z >= 0.0f) || !(r > 0.0f)) return;

    // pixel centers: xf(w) = 1 - (2w+1)/W; point touches pixel only if
    // |xf(w) - x| < r; bounds widened 1px for fp slop
    float wlo = (WW * (1.0f - x - r) - 1.0f) * 0.5f;
    float whi = (WW * (1.0f - x + r) - 1.0f) * 0.5f;
    int wmin = max(0, (int)ceilf(wlo - 1.0f));
    int wmax = min(WW - 1, (int)floorf(whi + 1.0f));
    float hlo = (HH * (1.0f - y - r) - 1.0f) * 0.5f;
    float hhi = (HH * (1.0f - y + r) - 1.0f) * 0.5f;
    int hmin = max(0, (int)ceilf(hlo - 1.0f));
    int hmax = min(HH - 1, (int)floorf(hhi + 1.0f));
    if (wmin > wmax || hmin > hmax) return;

    float4 rec = make_float4(x, y, z, __fmul_rn(r, r));

    int twmin = wmin / TILE, twmax = wmax / TILE;
    int thmin = hmin / TILE, thmax = hmax / TILE;
    for (int th = thmin; th <= thmax; ++th) {
        for (int tw = twmin; tw <= twmax; ++tw) {
            int t = th * TX + tw;
            int slot = atomicAdd(&counts[t], 1);
            if (slot < cap) {
                xyzr[t * cap + slot] = rec;
                pidx[t * cap + slot] = p;
            }
        }
    }
}

// conditional swap so the "lo" slot holds the lexicographic smaller (z, idx)
#define CSTEP(zh, ih, dh, zl, il, dl)                                 \
    {                                                                 \
        bool sw_ = (zh < zl) || (zh == zl && ih < il);                \
        float tz_ = sw_ ? zl : zh; int ti_ = sw_ ? il : ih;           \
        float td_ = sw_ ? dl : dh;                                    \
        zl = sw_ ? zh : zl; il = sw_ ? ih : il; dl = sw_ ? dh : dl;   \
        zh = tz_; ih = ti_; dh = td_;                                 \
    }

// one block = one 64-lane wave = one 8x8 pixel tile; no LDS, no arrays
__global__ void __launch_bounds__(64) raster_kernel(
                              const int* __restrict__ counts,
                              const float4* __restrict__ xyzr,
                              const int* __restrict__ pidx,
                              int cap,
                              float* __restrict__ out) {
    int t = blockIdx.x;
    int th = t / TX, tw = t % TX;
    int lane = threadIdx.x;
    int pw = lane % TILE, ph = lane / TILE;
    int w = tw * TILE + pw;
    int h = th * TILE + ph;

    float xf = 1.0f - (2.0f * (float)w + 1.0f) * (1.0f / (float)WW);
    float yf = 1.0f - (2.0f * (float)h + 1.0f) * (1.0f / (float)HH);

    // top-K state, fully scalarized -> guaranteed VGPRs (no indexable array)
    float z0 = INFINITY, z1 = INFINITY, z2 = INFINITY, z3 = INFINITY,
          z4 = INFINITY, z5 = INFINITY, z6 = INFINITY, z7 = INFINITY;
    int   i0 = IMAX, i1 = IMAX, i2 = IMAX, i3 = IMAX,
          i4 = IMAX, i5 = IMAX, i6 = IMAX, i7 = IMAX;
    float d0 = -1.f, d1 = -1.f, d2s = -1.f, d3 = -1.f,
          d4 = -1.f, d5 = -1.f, d6 = -1.f, d7 = -1.f;

    int cnt = min(counts[t], cap);
    const float4* tl = xyzr + (long)t * cap;
    const int*    ti = pidx + (long)t * cap;

    // register double-buffer: lane holds candidate (base + lane)
    float4 cur = make_float4(0.f, 0.f, 0.f, 0.f);
    int cpi = 0;
    if (lane < cnt) { cur = tl[lane]; cpi = ti[lane]; }

    for (int base = 0; base < cnt; base += 64) {
        int n = min(64, cnt - base);
        // prefetch next chunk while we chew on this one
        float4 nxt = make_float4(0.f, 0.f, 0.f, 0.f);
        int npi = 0;
        int nb = base + 64;
        if (nb + lane < cnt) { nxt = tl[nb + lane]; npi = ti[nb + lane]; }

        for (int j = 0; j < n; ++j) {
            float x  = bcastf(cur.x, j);
            float y  = bcastf(cur.y, j);
            float z  = bcastf(cur.z, j);
            float r2 = bcastf(cur.w, j);
            int   p  = bcasti(cpi, j);
            float dx = xf - x;
            float dy = yf - y;
            // match numpy rounding exactly: mul, mul, add (no fma contraction)
            float dd = __fadd_rn(__fmul_rn(dx, dx), __fmul_rn(dy, dy));
            if (dd < r2 && ((z < z7) || (z == z7 && p < i7))) {
                z7 = z; i7 = p; d7 = dd;
                CSTEP(z7, i7, d7, z6, i6, d6);
                CSTEP(z6, i6, d6, z5, i5, d5);
                CSTEP(z5, i5, d5, z4, i4, d4);
                CSTEP(z4, i4, d4, z3, i3, d3);
                CSTEP(z3, i3, d3, z2, i2, d2s);
                CSTEP(z2, i2, d2s, z1, i1, d1);
                CSTEP(z1, i1, d1, z0, i0, d0);
            }
        }
        cur = nxt; cpi = npi;
    }

    int pix = h * WW + w;
    float* o_idx = out;
    float* o_z   = out + HH * WW * KK;
    float* o_d   = out + 2 * HH * WW * KK;

    bool v0 = i0 != IMAX, v1 = i1 != IMAX, v2 = i2 != IMAX, v3 = i3 != IMAX;
    bool v4 = i4 != IMAX, v5 = i5 != IMAX, v6 = i6 != IMAX, v7 = i7 != IMAX;

    float4 fi_lo = make_float4(v0 ? (float)i0 : -1.f, v1 ? (float)i1 : -1.f,
                               v2 ? (float)i2 : -1.f, v3 ? (float)i3 : -1.f);
    float4 fi_hi = make_float4(v4 ? (float)i4 : -1.f, v5 ? (float)i5 : -1.f,
                               v6 ? (float)i6 : -1.f, v7 ? (float)i7 : -1.f);
    float4 fz_lo = make_float4(v0 ? z0 : -1.f, v1 ? z1 : -1.f,
                               v2 ? z2 : -1.f, v3 ? z3 : -1.f);
    float4 fz_hi = make_float4(v4 ? z4 : -1.f, v5 ? z5 : -1.f,
                               v6 ? z6 : -1.f, v7 ? z7 : -1.f);
    float4 fd_lo = make_float4(v0 ? d0 : -1.f, v1 ? d1 : -1.f,
                               v2 ? d2s : -1.f, v3 ? d3 : -1.f);
    float4 fd_hi = make_float4(v4 ? d4 : -1.f, v5 ? d5 : -1.f,
                               v6 ? d6 : -1.f, v7 ? d7 : -1.f);

    float4* oi = (float4*)(o_idx + pix * KK);
    float4* oz = (float4*)(o_z   + pix * KK);
    float4* od = (float4*)(o_d   + pix * KK);
    oi[0] = fi_lo; oi[1] = fi_hi;
    oz[0] = fz_lo; oz[1] = fz_hi;
    od[0] = fd_lo; od[1] = fd_hi;
}

extern "C" void kernel_launch(void* const* d_in, const int* in_sizes, int n_in,
                              void* d_out, int out_size, void* d_ws, size_t ws_size,
                              hipStream_t stream) {
    const float* pts = (const float*)d_in[0];   // (P,3) f32
    const float* rad = (const float*)d_in[1];   // (P,)  f32
    int P = in_sizes[0] / 3;

    int* counts = (int*)d_ws;
    // slot cost = 16B (float4) + 4B (idx) per tile entry
    long avail = (long)ws_size - 1024;
    int cap = (int)(avail / (NTILES * 20));
    if (cap > CAP_MAX) cap = CAP_MAX;
    if (cap < 1) cap = 1;
    float4* xyzr = (float4*)((char*)d_ws + 1024);
    int* pidx = (int*)(xyzr + (long)NTILES * cap);

    hipMemsetAsync(counts, 0, NTILES * sizeof(int), stream);
    bin_points_kernel<<<(P + 255) / 256, 256, 0, stream>>>(pts, rad, P, cap, counts, xyzr, pidx);
    raster_kernel<<<NTILES, 64, 0, stream>>>(counts, xyzr, pidx, cap, (float*)d_out);
}

// Round 5
// 38.894 us; speedup vs baseline: 2.6091x; 1.4968x over previous
//
#include <hip/hip_runtime.h>

#define HH 128
#define WW 128
#define KK 8
#define TILE 8
#define TX (WW / TILE)        // 16
#define TY (HH / TILE)        // 16
#define NTILES (TX * TY)      // 256
#define NWAVES 4
#define CAP_MAX 1024
#define IMAX 0x7fffffff

// ws layout: counts[NTILES] int (1 KB) | xyzr[NTILES*cap] float4 | pidx[NTILES*cap] int

__device__ __forceinline__ float bcastf(float v, int lane) {
    return __int_as_float(__builtin_amdgcn_readlane(__float_as_int(v), lane));
}
__device__ __forceinline__ int bcasti(int v, int lane) {
    return __builtin_amdgcn_readlane(v, lane);
}

__global__ void bin_points_kernel(const float* __restrict__ pts,
                                  const float* __restrict__ rad,
                                  int P, int cap,
                                  int* __restrict__ counts,
                                  float4* __restrict__ xyzr,
                                  int* __restrict__ pidx) {
    int p = blockIdx.x * blockDim.x + threadIdx.x;
    if (p >= P) return;

    float x = pts[3 * p + 0];
    float y = pts[3 * p + 1];
    float z = pts[3 * p + 2];
    float r = rad[p];
    if (!(z >= 0.0f) || !(r > 0.0f)) return;

    // pixel centers: xf(w) = 1 - (2w+1)/W; pixel can pass dist2<r^2 only if
    // |xf(w)-x| < r per axis. 0.05px margin >> f32 rounding error (~1e-3px).
    float wlo = (WW * (1.0f - x - r) - 1.0f) * 0.5f;
    float whi = (WW * (1.0f - x + r) - 1.0f) * 0.5f;
    int wmin = max(0, (int)ceilf(wlo - 0.05f));
    int wmax = min(WW - 1, (int)floorf(whi + 0.05f));
    float hlo = (HH * (1.0f - y - r) - 1.0f) * 0.5f;
    float hhi = (HH * (1.0f - y + r) - 1.0f) * 0.5f;
    int hmin = max(0, (int)ceilf(hlo - 0.05f));
    int hmax = min(HH - 1, (int)floorf(hhi + 0.05f));
    if (wmin > wmax || hmin > hmax) return;

    float4 rec = make_float4(x, y, z, __fmul_rn(r, r));

    int twmin = wmin / TILE, twmax = wmax / TILE;
    int thmin = hmin / TILE, thmax = hmax / TILE;
    for (int th = thmin; th <= thmax; ++th) {
        for (int tw = twmin; tw <= twmax; ++tw) {
            int t = th * TX + tw;
            int slot = atomicAdd(&counts[t], 1);
            if (slot < cap) {
                xyzr[t * cap + slot] = rec;
                pidx[t * cap + slot] = p;
            }
        }
    }
}

// conditional swap so the "lo" slot holds the lexicographic smaller (z, idx)
#define CSTEP(zh, ih, dh, zl, il, dl)                                 \
    {                                                                 \
        bool sw_ = (zh < zl) || (zh == zl && ih < il);                \
        float tz_ = sw_ ? zl : zh; int ti_ = sw_ ? il : ih;           \
        float td_ = sw_ ? dl : dh;                                    \
        zl = sw_ ? zh : zl; il = sw_ ? ih : il; dl = sw_ ? dh : dl;   \
        zh = tz_; ih = ti_; dh = td_;                                 \
    }

// full insert of (z,p,dd) into sorted 8-slot list
#define INSERT(z, p, dd)                                              \
    {                                                                 \
        z7 = z; i7 = p; d7 = dd;                                      \
        CSTEP(z7, i7, d7, z6, i6, d6);                                \
        CSTEP(z6, i6, d6, z5, i5, d5);                                \
        CSTEP(z5, i5, d5, z4, i4, d4);                                \
        CSTEP(z4, i4, d4, z3, i3, d3);                                \
        CSTEP(z3, i3, d3, z2, i2, d2s);                               \
        CSTEP(z2, i2, d2s, z1, i1, d1);                               \
        CSTEP(z1, i1, d1, z0, i0, d0);                                \
    }

// one block = 4 waves = one 8x8 pixel tile; each wave handles 1/4 of the
// candidate list for ALL 64 pixels; wave 0 merges via LDS at the end.
__global__ void __launch_bounds__(256) raster_kernel(
                              const int* __restrict__ counts,
                              const float4* __restrict__ xyzr,
                              const int* __restrict__ pidx,
                              int cap,
                              float* __restrict__ out) {
    int t = blockIdx.x;
    int th = t / TX, tw = t % TX;
    int wv = threadIdx.x >> 6;        // wave id 0..3
    int lane = threadIdx.x & 63;      // pixel id within tile
    int pw = lane % TILE, ph = lane / TILE;
    int w = tw * TILE + pw;
    int h = th * TILE + ph;

    float xf = 1.0f - (2.0f * (float)w + 1.0f) * (1.0f / (float)WW);
    float yf = 1.0f - (2.0f * (float)h + 1.0f) * (1.0f / (float)HH);

    // [wave-1][k][pixel] layout: lane-stride 4B -> conflict-free
    __shared__ float lz[NWAVES - 1][KK][64];
    __shared__ int   li[NWAVES - 1][KK][64];
    __shared__ float ld[NWAVES - 1][KK][64];

    // top-K state, fully scalarized -> guaranteed VGPRs
    float z0 = INFINITY, z1 = INFINITY, z2 = INFINITY, z3 = INFINITY,
          z4 = INFINITY, z5 = INFINITY, z6 = INFINITY, z7 = INFINITY;
    int   i0 = IMAX, i1 = IMAX, i2 = IMAX, i3 = IMAX,
          i4 = IMAX, i5 = IMAX, i6 = IMAX, i7 = IMAX;
    float d0 = -1.f, d1 = -1.f, d2s = -1.f, d3 = -1.f,
          d4 = -1.f, d5 = -1.f, d6 = -1.f, d7 = -1.f;

    int cnt = min(counts[t], cap);
    const float4* tl = xyzr + (long)t * cap;
    const int*    ti = pidx + (long)t * cap;

    // this wave's contiguous slice
    int S = (cnt + NWAVES - 1) / NWAVES;
    int s0 = wv * S;
    int s1 = min(cnt, s0 + S);

    for (int base = s0; base < s1; base += 64) {
        int n = min(64, s1 - base);
        float4 cur = make_float4(0.f, 0.f, 0.f, 0.f);
        int cpi = 0;
        if (base + lane < s1) { cur = tl[base + lane]; cpi = ti[base + lane]; }

        for (int j = 0; j < n; ++j) {
            float x  = bcastf(cur.x, j);
            float y  = bcastf(cur.y, j);
            float z  = bcastf(cur.z, j);
            float r2 = bcastf(cur.w, j);
            int   p  = bcasti(cpi, j);
            float dx = xf - x;
            float dy = yf - y;
            // match numpy rounding exactly: mul, mul, add (no fma contraction)
            float dd = __fadd_rn(__fmul_rn(dx, dx), __fmul_rn(dy, dy));
            if (dd < r2 && ((z < z7) || (z == z7 && p < i7))) {
                INSERT(z, p, dd);
            }
        }
    }

    // waves 1..3 publish their lists; wave 0 merges
    if (wv > 0) {
        int m = wv - 1;
        lz[m][0][lane] = z0; li[m][0][lane] = i0; ld[m][0][lane] = d0;
        lz[m][1][lane] = z1; li[m][1][lane] = i1; ld[m][1][lane] = d1;
        lz[m][2][lane] = z2; li[m][2][lane] = i2; ld[m][2][lane] = d2s;
        lz[m][3][lane] = z3; li[m][3][lane] = i3; ld[m][3][lane] = d3;
        lz[m][4][lane] = z4; li[m][4][lane] = i4; ld[m][4][lane] = d4;
        lz[m][5][lane] = z5; li[m][5][lane] = i5; ld[m][5][lane] = d5;
        lz[m][6][lane] = z6; li[m][6][lane] = i6; ld[m][6][lane] = d6;
        lz[m][7][lane] = z7; li[m][7][lane] = i7; ld[m][7][lane] = d7;
    }
    __syncthreads();
    if (wv != 0) return;

#pragma unroll
    for (int m = 0; m < NWAVES - 1; ++m) {
        for (int k = 0; k < KK; ++k) {
            float z = lz[m][k][lane];
            int   p = li[m][k][lane];
            float dd = ld[m][k][lane];
            bool ins = (z < z7) || (z == z7 && p < i7);
            // incoming list sorted ascending; once nobody inserts, rest can't
            if (!__builtin_amdgcn_ballot_w64(ins)) break;
            if (ins) INSERT(z, p, dd);
        }
    }

    int pix = h * WW + w;
    float* o_idx = out;
    float* o_z   = out + HH * WW * KK;
    float* o_d   = out + 2 * HH * WW * KK;

    bool v0 = i0 != IMAX, v1 = i1 != IMAX, v2 = i2 != IMAX, v3 = i3 != IMAX;
    bool v4 = i4 != IMAX, v5 = i5 != IMAX, v6 = i6 != IMAX, v7 = i7 != IMAX;

    float4 fi_lo = make_float4(v0 ? (float)i0 : -1.f, v1 ? (float)i1 : -1.f,
                               v2 ? (float)i2 : -1.f, v3 ? (float)i3 : -1.f);
    float4 fi_hi = make_float4(v4 ? (float)i4 : -1.f, v5 ? (float)i5 : -1.f,
                               v6 ? (float)i6 : -1.f, v7 ? (float)i7 : -1.f);
    float4 fz_lo = make_float4(v0 ? z0 : -1.f, v1 ? z1 : -1.f,
                               v2 ? z2 : -1.f, v3 ? z3 : -1.f);
    float4 fz_hi = make_float4(v4 ? z4 : -1.f, v5 ? z5 : -1.f,
                               v6 ? z6 : -1.f, v7 ? z7 : -1.f);
    float4 fd_lo = make_float4(v0 ? d0 : -1.f, v1 ? d1 : -1.f,
                               v2 ? d2s : -1.f, v3 ? d3 : -1.f);
    float4 fd_hi = make_float4(v4 ? d4 : -1.f, v5 ? d5 : -1.f,
                               v6 ? d6 : -1.f, v7 ? d7 : -1.f);

    float4* oi = (float4*)(o_idx + pix * KK);
    float4* oz = (float4*)(o_z   + pix * KK);
    float4* od = (float4*)(o_d   + pix * KK);
    oi[0] = fi_lo; oi[1] = fi_hi;
    oz[0] = fz_lo; oz[1] = fz_hi;
    od[0] = fd_lo; od[1] = fd_hi;
}

extern "C" void kernel_launch(void* const* d_in, const int* in_sizes, int n_in,
                              void* d_out, int out_size, void* d_ws, size_t ws_size,
                              hipStream_t stream) {
    const float* pts = (const float*)d_in[0];   // (P,3) f32
    const float* rad = (const float*)d_in[1];   // (P,)  f32
    int P = in_sizes[0] / 3;

    int* counts = (int*)d_ws;
    // slot cost = 16B (float4) + 4B (idx) per tile entry
    long avail = (long)ws_size - 1024;
    int cap = (int)(avail / (NTILES * 20));
    if (cap > CAP_MAX) cap = CAP_MAX;
    if (cap < 1) cap = 1;
    float4* xyzr = (float4*)((char*)d_ws + 1024);
    int* pidx = (int*)(xyzr + (long)NTILES * cap);

    hipMemsetAsync(counts, 0, NTILES * sizeof(int), stream);
    bin_points_kernel<<<(P + 255) / 256, 256, 0, stream>>>(pts, rad, P, cap, counts, xyzr, pidx);
    raster_kernel<<<NTILES, 256, 0, stream>>>(counts, xyzr, pidx, cap, (float*)d_out);
}

// Round 6
// 31.957 us; speedup vs baseline: 3.1754x; 1.2171x over previous
//
#include <hip/hip_runtime.h>

#define HH 128
#define WW 128
#define KK 8
#define TILE 8
#define TX (WW / TILE)        // 16
#define TY (HH / TILE)        // 16
#define NTILES (TX * TY)      // 256
#define NWAVES 4
#define CAP 1024
#define IMAX 0x7fffffff

__device__ __forceinline__ float bcastf(float v, int lane) {
    return __int_as_float(__builtin_amdgcn_readlane(__float_as_int(v), lane));
}
__device__ __forceinline__ int bcasti(int v, int lane) {
    return __builtin_amdgcn_readlane(v, lane);
}

// conditional swap so the "lo" slot holds the lexicographic smaller (z, idx)
#define CSTEP(zh, ih, dh, zl, il, dl)                                 \
    {                                                                 \
        bool sw_ = (zh < zl) || (zh == zl && ih < il);                \
        float tz_ = sw_ ? zl : zh; int ti_ = sw_ ? il : ih;           \
        float td_ = sw_ ? dl : dh;                                    \
        zl = sw_ ? zh : zl; il = sw_ ? ih : il; dl = sw_ ? dh : dl;   \
        zh = tz_; ih = ti_; dh = td_;                                 \
    }

// full insert of (z,p,dd) into sorted 8-slot list
#define INSERT(z, p, dd)                                              \
    {                                                                 \
        z7 = z; i7 = p; d7 = dd;                                      \
        CSTEP(z7, i7, d7, z6, i6, d6);                                \
        CSTEP(z6, i6, d6, z5, i5, d5);                                \
        CSTEP(z5, i5, d5, z4, i4, d4);                                \
        CSTEP(z4, i4, d4, z3, i3, d3);                                \
        CSTEP(z3, i3, d3, z2, i2, d2s);                               \
        CSTEP(z2, i2, d2s, z1, i1, d1);                               \
        CSTEP(z1, i1, d1, z0, i0, d0);                                \
    }

// ONE kernel. One block per 8x8 tile (256 blocks = 1/CU). Phase A: all 256
// threads scan the full point list, filter to this tile, append to LDS.
// Phase B: 4 waves split the LDS candidate list, register top-K each,
// wave 0 merges. Selection is exact lexicographic (z, idx) -> append order
// (nondeterministic atomics) cannot change the result.
__global__ void __launch_bounds__(256) fused_raster_kernel(
                              const float* __restrict__ pts,
                              const float* __restrict__ rad,
                              int P,
                              float* __restrict__ out) {
    int t = blockIdx.x;
    int th = t / TX, tw = t % TX;
    int tid = threadIdx.x;
    int wv = tid >> 6;            // wave id 0..3
    int lane = tid & 63;          // pixel id within tile
    int pw = lane % TILE, ph = lane / TILE;
    int w = tw * TILE + pw;
    int h = th * TILE + ph;

    __shared__ float4 scand[CAP];
    __shared__ int    sidx[CAP];
    __shared__ int    scnt;
    __shared__ float lz[NWAVES - 1][KK][64];
    __shared__ int   li[NWAVES - 1][KK][64];
    __shared__ float ld[NWAVES - 1][KK][64];

    if (tid == 0) scnt = 0;
    __syncthreads();

    // ---- Phase A: filter all points against this tile ----
    for (int p = tid; p < P; p += 256) {
        float x = pts[3 * p + 0];
        float y = pts[3 * p + 1];
        float z = pts[3 * p + 2];
        float r = rad[p];
        if (!(z >= 0.0f) || !(r > 0.0f)) continue;

        // pixel centers: xf(w) = 1 - (2w+1)/W; pixel can pass dist2<r^2 only
        // if |xf(w)-x| < r per axis. 0.05px margin >> f32 error (~1e-3px).
        float wlo = (WW * (1.0f - x - r) - 1.0f) * 0.5f;
        float whi = (WW * (1.0f - x + r) - 1.0f) * 0.5f;
        int wmin = max(0, (int)ceilf(wlo - 0.05f));
        int wmax = min(WW - 1, (int)floorf(whi + 0.05f));
        float hlo = (HH * (1.0f - y - r) - 1.0f) * 0.5f;
        float hhi = (HH * (1.0f - y + r) - 1.0f) * 0.5f;
        int hmin = max(0, (int)ceilf(hlo - 0.05f));
        int hmax = min(HH - 1, (int)floorf(hhi + 0.05f));
        if (wmin > wmax || hmin > hmax) continue;
        if (tw < wmin / TILE || tw > wmax / TILE) continue;
        if (th < hmin / TILE || th > hmax / TILE) continue;

        int slot = atomicAdd(&scnt, 1);
        if (slot < CAP) {
            scand[slot] = make_float4(x, y, z, __fmul_rn(r, r));
            sidx[slot] = p;
        }
    }
    __syncthreads();
    int cnt = min(scnt, CAP);

    // ---- Phase B: per-wave register top-K over a slice ----
    float z0 = INFINITY, z1 = INFINITY, z2 = INFINITY, z3 = INFINITY,
          z4 = INFINITY, z5 = INFINITY, z6 = INFINITY, z7 = INFINITY;
    int   i0 = IMAX, i1 = IMAX, i2 = IMAX, i3 = IMAX,
          i4 = IMAX, i5 = IMAX, i6 = IMAX, i7 = IMAX;
    float d0 = -1.f, d1 = -1.f, d2s = -1.f, d3 = -1.f,
          d4 = -1.f, d5 = -1.f, d6 = -1.f, d7 = -1.f;

    float xf = 1.0f - (2.0f * (float)w + 1.0f) * (1.0f / (float)WW);
    float yf = 1.0f - (2.0f * (float)h + 1.0f) * (1.0f / (float)HH);

    int S = (cnt + NWAVES - 1) / NWAVES;
    int s0 = wv * S;
    int s1 = min(cnt, s0 + S);

    for (int base = s0; base < s1; base += 64) {
        int n = min(64, s1 - base);
        float4 cur = make_float4(0.f, 0.f, 0.f, 0.f);
        int cpi = 0;
        if (base + lane < s1) { cur = scand[base + lane]; cpi = sidx[base + lane]; }

        for (int j = 0; j < n; ++j) {
            float x  = bcastf(cur.x, j);
            float y  = bcastf(cur.y, j);
            float z  = bcastf(cur.z, j);
            float r2 = bcastf(cur.w, j);
            int   p  = bcasti(cpi, j);
            float dx = xf - x;
            float dy = yf - y;
            // match numpy rounding exactly: mul, mul, add (no fma contraction)
            float dd = __fadd_rn(__fmul_rn(dx, dx), __fmul_rn(dy, dy));
            if (dd < r2 && ((z < z7) || (z == z7 && p < i7))) {
                INSERT(z, p, dd);
            }
        }
    }

    // waves 1..3 publish their lists; wave 0 merges
    if (wv > 0) {
        int m = wv - 1;
        lz[m][0][lane] = z0; li[m][0][lane] = i0; ld[m][0][lane] = d0;
        lz[m][1][lane] = z1; li[m][1][lane] = i1; ld[m][1][lane] = d1;
        lz[m][2][lane] = z2; li[m][2][lane] = i2; ld[m][2][lane] = d2s;
        lz[m][3][lane] = z3; li[m][3][lane] = i3; ld[m][3][lane] = d3;
        lz[m][4][lane] = z4; li[m][4][lane] = i4; ld[m][4][lane] = d4;
        lz[m][5][lane] = z5; li[m][5][lane] = i5; ld[m][5][lane] = d5;
        lz[m][6][lane] = z6; li[m][6][lane] = i6; ld[m][6][lane] = d6;
        lz[m][7][lane] = z7; li[m][7][lane] = i7; ld[m][7][lane] = d7;
    }
    __syncthreads();
    if (wv != 0) return;

#pragma unroll
    for (int m = 0; m < NWAVES - 1; ++m) {
        for (int k = 0; k < KK; ++k) {
            float z = lz[m][k][lane];
            int   p = li[m][k][lane];
            float dd = ld[m][k][lane];
            bool ins = (z < z7) || (z == z7 && p < i7);
            // incoming list sorted ascending; once nobody inserts, rest can't
            if (!__builtin_amdgcn_ballot_w64(ins)) break;
            if (ins) INSERT(z, p, dd);
        }
    }

    int pix = h * WW + w;
    float* o_idx = out;
    float* o_z   = out + HH * WW * KK;
    float* o_d   = out + 2 * HH * WW * KK;

    bool v0 = i0 != IMAX, v1 = i1 != IMAX, v2 = i2 != IMAX, v3 = i3 != IMAX;
    bool v4 = i4 != IMAX, v5 = i5 != IMAX, v6 = i6 != IMAX, v7 = i7 != IMAX;

    float4 fi_lo = make_float4(v0 ? (float)i0 : -1.f, v1 ? (float)i1 : -1.f,
                               v2 ? (float)i2 : -1.f, v3 ? (float)i3 : -1.f);
    float4 fi_hi = make_float4(v4 ? (float)i4 : -1.f, v5 ? (float)i5 : -1.f,
                               v6 ? (float)i6 : -1.f, v7 ? (float)i7 : -1.f);
    float4 fz_lo = make_float4(v0 ? z0 : -1.f, v1 ? z1 : -1.f,
                               v2 ? z2 : -1.f, v3 ? z3 : -1.f);
    float4 fz_hi = make_float4(v4 ? z4 : -1.f, v5 ? z5 : -1.f,
                               v6 ? z6 : -1.f, v7 ? z7 : -1.f);
    float4 fd_lo = make_float4(v0 ? d0 : -1.f, v1 ? d1 : -1.f,
                               v2 ? d2s : -1.f, v3 ? d3 : -1.f);
    float4 fd_hi = make_float4(v4 ? d4 : -1.f, v5 ? d5 : -1.f,
                               v6 ? d6 : -1.f, v7 ? d7 : -1.f);

    float4* oi = (float4*)(o_idx + pix * KK);
    float4* oz = (float4*)(o_z   + pix * KK);
    float4* od = (float4*)(o_d   + pix * KK);
    oi[0] = fi_lo; oi[1] = fi_hi;
    oz[0] = fz_lo; oz[1] = fz_hi;
    od[0] = fd_lo; od[1] = fd_hi;
}

extern "C" void kernel_launch(void* const* d_in, const int* in_sizes, int n_in,
                              void* d_out, int out_size, void* d_ws, size_t ws_size,
                              hipStream_t stream) {
    const float* pts = (const float*)d_in[0];   // (P,3) f32
    const float* rad = (const float*)d_in[1];   // (P,)  f32
    int P = in_sizes[0] / 3;

    fused_raster_kernel<<<NTILES, 256, 0, stream>>>(pts, rad, P, (float*)d_out);
}

// Round 7
// 27.317 us; speedup vs baseline: 3.7148x; 1.1699x over previous
//
#include <hip/hip_runtime.h>

#define HH 128
#define WW 128
#define KK 8
#define TILE 8
#define TX (WW / TILE)        // 16
#define TY (HH / TILE)        // 16
#define NTILES (TX * TY)      // 256
#define NW 8                  // waves per block
#define NT 512                // threads per block
#define CAP 1024
#define IMAX 0x7fffffff
#define EPS 1e-3f

__device__ __forceinline__ float bcastf(float v, int lane) {
    return __int_as_float(__builtin_amdgcn_readlane(__float_as_int(v), lane));
}
__device__ __forceinline__ int bcasti(int v, int lane) {
    return __builtin_amdgcn_readlane(v, lane);
}

// conditional swap so the "lo" slot holds the lexicographic smaller (z, idx)
#define CSTEP(zh, ih, dh, zl, il, dl)                                 \
    {                                                                 \
        bool sw_ = (zh < zl) || (zh == zl && ih < il);                \
        float tz_ = sw_ ? zl : zh; int ti_ = sw_ ? il : ih;           \
        float td_ = sw_ ? dl : dh;                                    \
        zl = sw_ ? zh : zl; il = sw_ ? ih : il; dl = sw_ ? dh : dl;   \
        zh = tz_; ih = ti_; dh = td_;                                 \
    }

// full insert of (z,p,dd) into sorted 8-slot list
#define INSERT(z, p, dd)                                              \
    {                                                                 \
        z7 = z; i7 = p; d7 = dd;                                      \
        CSTEP(z7, i7, d7, z6, i6, d6);                                \
        CSTEP(z6, i6, d6, z5, i5, d5);                                \
        CSTEP(z5, i5, d5, z4, i4, d4);                                \
        CSTEP(z4, i4, d4, z3, i3, d3);                                \
        CSTEP(z3, i3, d3, z2, i2, d2s);                               \
        CSTEP(z2, i2, d2s, z1, i1, d1);                               \
        CSTEP(z1, i1, d1, z0, i0, d0);                                \
    }

// ONE kernel. One block per 8x8 tile. Phase A: 512 threads scan all points
// (4-point batched loads), filter with a cheap tile-rect test, append to LDS.
// Phase B: 8 waves each top-K a slice; wave 0 merges. Selection is exact
// lexicographic (z, idx) -> LDS append order cannot change the result.
__global__ void __launch_bounds__(NT) fused_raster_kernel(
                              const float* __restrict__ pts,
                              const float* __restrict__ rad,
                              int P,
                              float* __restrict__ out) {
    int t = blockIdx.x;
    int th = t / TX, tw = t % TX;
    int tid = threadIdx.x;
    int wv = tid >> 6;            // wave id 0..7
    int lane = tid & 63;          // pixel id within tile
    int pw = lane % TILE, ph = lane / TILE;
    int w = tw * TILE + pw;
    int h = th * TILE + ph;

    __shared__ float4 scand[CAP];
    __shared__ int    sidx[CAP];
    __shared__ int    scnt;
    __shared__ float lz[NW - 1][KK][64];
    __shared__ int   li[NW - 1][KK][64];
    __shared__ float ld[NW - 1][KK][64];

    if (tid == 0) scnt = 0;
    __syncthreads();

    // tile pixel-center bounds (uniform per block). xf(w) = 1-(2w+1)/128,
    // decreasing in w; yf likewise in h. 1/128 exact -> bitwise == reference.
    float xhi_c = 1.0f - (2.0f * (float)(tw * TILE) + 1.0f) * (1.0f / WW);
    float xlo_c = 1.0f - (2.0f * (float)(tw * TILE + TILE - 1) + 1.0f) * (1.0f / WW);
    float yhi_c = 1.0f - (2.0f * (float)(th * TILE) + 1.0f) * (1.0f / HH);
    float ylo_c = 1.0f - (2.0f * (float)(th * TILE + TILE - 1) + 1.0f) * (1.0f / HH);

    // ---- Phase A: filter all points against this tile's rect (+r+eps) ----
    for (int base = 0; base < P; base += NT * 4) {
        int p0 = base + tid;
        int p1 = p0 + NT, p2 = p0 + 2 * NT, p3 = p0 + 3 * NT;
        bool g0 = p0 < P, g1 = p1 < P, g2 = p2 < P, g3 = p3 < P;
        // issue all 16 loads up front (independent -> one latency exposure)
        float x0 = g0 ? pts[3 * p0] : 2.f, y0 = g0 ? pts[3 * p0 + 1] : 2.f,
              zz0 = g0 ? pts[3 * p0 + 2] : -1.f, r0 = g0 ? rad[p0] : 0.f;
        float x1 = g1 ? pts[3 * p1] : 2.f, y1 = g1 ? pts[3 * p1 + 1] : 2.f,
              zz1 = g1 ? pts[3 * p1 + 2] : -1.f, r1 = g1 ? rad[p1] : 0.f;
        float x2 = g2 ? pts[3 * p2] : 2.f, y2 = g2 ? pts[3 * p2 + 1] : 2.f,
              zz2 = g2 ? pts[3 * p2 + 2] : -1.f, r2v = g2 ? rad[p2] : 0.f;
        float x3 = g3 ? pts[3 * p3] : 2.f, y3 = g3 ? pts[3 * p3 + 1] : 2.f,
              zz3 = g3 ? pts[3 * p3 + 2] : -1.f, r3 = g3 ? rad[p3] : 0.f;

#define CONSIDER(p, x, y, z, r)                                           \
        if ((z >= 0.0f) && (r > 0.0f) &&                                  \
            (x > xlo_c - r - EPS) && (x < xhi_c + r + EPS) &&             \
            (y > ylo_c - r - EPS) && (y < yhi_c + r + EPS)) {             \
            int slot = atomicAdd(&scnt, 1);                               \
            if (slot < CAP) {                                             \
                scand[slot] = make_float4(x, y, z, __fmul_rn(r, r));      \
                sidx[slot] = p;                                           \
            }                                                             \
        }

        CONSIDER(p0, x0, y0, zz0, r0)
        CONSIDER(p1, x1, y1, zz1, r1)
        CONSIDER(p2, x2, y2, zz2, r2v)
        CONSIDER(p3, x3, y3, zz3, r3)
#undef CONSIDER
    }
    __syncthreads();
    int cnt = min(scnt, CAP);

    // ---- Phase B: per-wave register top-K over a slice ----
    float z0 = INFINITY, z1 = INFINITY, z2 = INFINITY, z3 = INFINITY,
          z4 = INFINITY, z5 = INFINITY, z6 = INFINITY, z7 = INFINITY;
    int   i0 = IMAX, i1 = IMAX, i2 = IMAX, i3 = IMAX,
          i4 = IMAX, i5 = IMAX, i6 = IMAX, i7 = IMAX;
    float d0 = -1.f, d1 = -1.f, d2s = -1.f, d3 = -1.f,
          d4 = -1.f, d5 = -1.f, d6 = -1.f, d7 = -1.f;

    float xf = 1.0f - (2.0f * (float)w + 1.0f) * (1.0f / (float)WW);
    float yf = 1.0f - (2.0f * (float)h + 1.0f) * (1.0f / (float)HH);

    int S = (cnt + NW - 1) / NW;
    int s0 = wv * S;
    int s1 = min(cnt, s0 + S);

    for (int base = s0; base < s1; base += 64) {
        int n = min(64, s1 - base);
        float4 cur = make_float4(0.f, 0.f, 0.f, 0.f);
        int cpi = 0;
        if (base + lane < s1) { cur = scand[base + lane]; cpi = sidx[base + lane]; }

        for (int j = 0; j < n; ++j) {
            float x  = bcastf(cur.x, j);
            float y  = bcastf(cur.y, j);
            float z  = bcastf(cur.z, j);
            float r2 = bcastf(cur.w, j);
            int   p  = bcasti(cpi, j);
            float dx = xf - x;
            float dy = yf - y;
            // match numpy rounding exactly: mul, mul, add (no fma contraction)
            float dd = __fadd_rn(__fmul_rn(dx, dx), __fmul_rn(dy, dy));
            if (dd < r2 && ((z < z7) || (z == z7 && p < i7))) {
                INSERT(z, p, dd);
            }
        }
    }

    // waves 1..7 publish their lists; wave 0 merges
    if (wv > 0) {
        int m = wv - 1;
        lz[m][0][lane] = z0; li[m][0][lane] = i0; ld[m][0][lane] = d0;
        lz[m][1][lane] = z1; li[m][1][lane] = i1; ld[m][1][lane] = d1;
        lz[m][2][lane] = z2; li[m][2][lane] = i2; ld[m][2][lane] = d2s;
        lz[m][3][lane] = z3; li[m][3][lane] = i3; ld[m][3][lane] = d3;
        lz[m][4][lane] = z4; li[m][4][lane] = i4; ld[m][4][lane] = d4;
        lz[m][5][lane] = z5; li[m][5][lane] = i5; ld[m][5][lane] = d5;
        lz[m][6][lane] = z6; li[m][6][lane] = i6; ld[m][6][lane] = d6;
        lz[m][7][lane] = z7; li[m][7][lane] = i7; ld[m][7][lane] = d7;
    }
    __syncthreads();
    if (wv != 0) return;

#pragma unroll
    for (int m = 0; m < NW - 1; ++m) {
        for (int k = 0; k < KK; ++k) {
            float z = lz[m][k][lane];
            int   p = li[m][k][lane];
            float dd = ld[m][k][lane];
            bool ins = (z < z7) || (z == z7 && p < i7);
            // incoming list sorted ascending; once nobody inserts, rest can't
            if (!__builtin_amdgcn_ballot_w64(ins)) break;
            if (ins) INSERT(z, p, dd);
        }
    }

    int pix = h * WW + w;
    float* o_idx = out;
    float* o_z   = out + HH * WW * KK;
    float* o_d   = out + 2 * HH * WW * KK;

    bool v0 = i0 != IMAX, v1 = i1 != IMAX, v2 = i2 != IMAX, v3 = i3 != IMAX;
    bool v4 = i4 != IMAX, v5 = i5 != IMAX, v6 = i6 != IMAX, v7 = i7 != IMAX;

    float4 fi_lo = make_float4(v0 ? (float)i0 : -1.f, v1 ? (float)i1 : -1.f,
                               v2 ? (float)i2 : -1.f, v3 ? (float)i3 : -1.f);
    float4 fi_hi = make_float4(v4 ? (float)i4 : -1.f, v5 ? (float)i5 : -1.f,
                               v6 ? (float)i6 : -1.f, v7 ? (float)i7 : -1.f);
    float4 fz_lo = make_float4(v0 ? z0 : -1.f, v1 ? z1 : -1.f,
                               v2 ? z2 : -1.f, v3 ? z3 : -1.f);
    float4 fz_hi = make_float4(v4 ? z4 : -1.f, v5 ? z5 : -1.f,
                               v6 ? z6 : -1.f, v7 ? z7 : -1.f);
    float4 fd_lo = make_float4(v0 ? d0 : -1.f, v1 ? d1 : -1.f,
                               v2 ? d2s : -1.f, v3 ? d3 : -1.f);
    float4 fd_hi = make_float4(v4 ? d4 : -1.f, v5 ? d5 : -1.f,
                               v6 ? d6 : -1.f, v7 ? d7 : -1.f);

    float4* oi = (float4*)(o_idx + pix * KK);
    float4* oz = (float4*)(o_z   + pix * KK);
    float4* od = (float4*)(o_d   + pix * KK);
    oi[0] = fi_lo; oi[1] = fi_hi;
    oz[0] = fz_lo; oz[1] = fz_hi;
    od[0] = fd_lo; od[1] = fd_hi;
}

extern "C" void kernel_launch(void* const* d_in, const int* in_sizes, int n_in,
                              void* d_out, int out_size, void* d_ws, size_t ws_size,
                              hipStream_t stream) {
    const float* pts = (const float*)d_in[0];   // (P,3) f32
    const float* rad = (const float*)d_in[1];   // (P,)  f32
    int P = in_sizes[0] / 3;
    (void)d_ws; (void)ws_size;

    fused_raster_kernel<<<NTILES, NT, 0, stream>>>(pts, rad, P, (float*)d_out);
}